// Round 6
// baseline (4604.068 us; speedup 1.0000x reference)
//
#include <hip/hip_runtime.h>
#include <hip/hip_bf16.h>

typedef float f32x4 __attribute__((ext_vector_type(4)));
typedef short s16x8 __attribute__((ext_vector_type(8)));
typedef short s16x4 __attribute__((ext_vector_type(4)));

#define REP_PREP 192
#define REP_QKVG 128
#define REP_ZB   5
#define REP_ATTN 24
#define REP_OUT  128

__device__ __forceinline__ unsigned short f2bf(float x){
  unsigned u = __float_as_uint(x);
  u += 0x7fffu + ((u >> 16) & 1u);
  return (unsigned short)(u >> 16);
}
__device__ __forceinline__ float bf2f(unsigned short h){
  return __uint_as_float(((unsigned)h) << 16);
}
__device__ __forceinline__ unsigned pk_bf(float a, float b){
  __hip_bfloat162 t = __float22bfloat162_rn(make_float2(a, b));
  return *reinterpret_cast<unsigned*>(&t);
}

// ---------------- prep: weight transpose->bf16 (0..179), ln_a (180..435), setup (436) ----------------
__global__ __launch_bounds__(256) void prep_kernel(const float* __restrict__ a, const float* __restrict__ ln_a_w,
                             const float* __restrict__ ln_a_b, const float* __restrict__ lnzw,
                             const float* __restrict__ lnzb, const float* __restrict__ w_z,
                             const float* __restrict__ wq, const float* __restrict__ wk,
                             const float* __restrict__ wv, const float* __restrict__ wg,
                             const float* __restrict__ wo,
                             unsigned short* __restrict__ a_lnB, unsigned short* __restrict__ wBall,
                             unsigned short* __restrict__ wwB, float* __restrict__ TU, long roff){
  int bid = blockIdx.x, tid = threadIdx.x;
  if (bid < 180){
    __shared__ float t[64][65];
    int mat = bid/36, tt = bid - mat*36;
    int c0 = (tt % 6)*64, k0 = (tt / 6)*64;
    const float* src0 = mat == 0 ? wq : mat == 1 ? wk : mat == 2 ? wv : mat == 3 ? wg : wo;
    for (int rep = 0; rep < REP_PREP; ++rep){
      const float* src = src0 + (size_t)rep*roff;
      int r = tid >> 4, c4 = (tid & 15)*4;
      #pragma unroll
      for (int rr = 0; rr < 4; ++rr){
        float4 v = *(const float4*)(src + (size_t)(k0 + r + rr*16)*384 + c0 + c4);
        t[r + rr*16][c4+0] = v.x; t[r + rr*16][c4+1] = v.y;
        t[r + rr*16][c4+2] = v.z; t[r + rr*16][c4+3] = v.w;
      }
      __syncthreads();
      float scale = (mat == 0) ? 0.20412414523193154f : 1.f;
      int cc = tid >> 2, kp = (tid & 3)*16;
      unsigned ow[8];
      #pragma unroll
      for (int j = 0; j < 8; ++j)
        ow[j] = pk_bf(t[kp + 2*j][cc]*scale, t[kp + 2*j + 1][cc]*scale);
      unsigned short* dst = wBall + ((size_t)(mat*384 + c0 + cc)*384 + k0 + kp);
      *(uint4*)dst       = make_uint4(ow[0], ow[1], ow[2], ow[3]);
      *(uint4*)(dst + 8) = make_uint4(ow[4], ow[5], ow[6], ow[7]);
      __syncthreads();
    }
  } else if (bid < 436){
    for (int rep = 0; rep < REP_PREP; ++rep){
      const float* ab = a + (size_t)rep*roff;
      int r = (bid - 180)*4 + (tid >> 6), l = tid & 63;
      const float* ap = ab + (size_t)r*384;
      float x[6]; float s = 0.f, sq = 0.f;
      #pragma unroll
      for (int i = 0; i < 6; ++i){ x[i] = ap[i*64 + l]; s += x[i]; sq += x[i]*x[i]; }
      #pragma unroll
      for (int off = 32; off; off >>= 1){ s += __shfl_xor(s, off); sq += __shfl_xor(sq, off); }
      float mu = s*(1.f/384.f);
      float var = sq*(1.f/384.f) - mu*mu;
      float rs = rsqrtf(var + 1e-5f);
      #pragma unroll
      for (int i = 0; i < 6; ++i){ int c = i*64 + l; a_lnB[(size_t)r*384 + c] = f2bf((x[i]-mu)*rs*ln_a_w[c] + ln_a_b[c]); }
    }
  } else {
    for (int rep = 0; rep < REP_PREP; ++rep){
      const float* zw = lnzw + (size_t)rep*roff;
      if (tid < 128){
        float lw = zw[tid];
        #pragma unroll
        for (int h = 0; h < 16; ++h) wwB[tid*16 + h] = f2bf(lw * w_z[tid*16 + h]);
      }
      if (tid < 16){
        float T = 0.f, U = 0.f;
        for (int c = 0; c < 128; ++c){ T += zw[c]*w_z[c*16 + tid]; U += lnzb[c]*w_z[c*16 + tid]; }
        TU[tid] = T; TU[16 + tid] = U;
      }
    }
  }
}

// ---------------- fused QKVG: [1024x384]bf16 @ [384x1536]bf16 via MFMA ----------------
__global__ __launch_bounds__(256) void qkvg_kernel(const unsigned short* __restrict__ AB,
                                                   const unsigned short* __restrict__ wBt,
                                                   const float* __restrict__ bg,
                                                   float* __restrict__ qT, float* __restrict__ kT,
                                                   float* __restrict__ vT, float* __restrict__ g, long roff){
  __shared__ short Al[64*8*8];
  __shared__ short Bl[64*8*8];
  int tid = threadIdx.x;
  int wave = tid >> 6, lane = tid & 63, l15 = lane & 15, sub = lane >> 4;
  int n0 = blockIdx.x*64, m0 = blockIdx.y*64;
  s16x8* Al8 = (s16x8*)Al; s16x8* Bl8 = (s16x8*)Bl;
  for (int rep = 0; rep < REP_QKVG; ++rep){
    const s16x8* Ag = (const s16x8*)(AB + (size_t)rep*roff);
    const s16x8* Bg = (const s16x8*)(wBt + (size_t)rep*roff);
    f32x4 acc[4];
    #pragma unroll
    for (int c = 0; c < 4; ++c) acc[c] = (f32x4){0.f,0.f,0.f,0.f};
    for (int ks = 0; ks < 6; ++ks){
      int k0u = ks*8;
      #pragma unroll
      for (int j = 0; j < 2; ++j){
        int idx = tid*2 + j;
        int row = idx >> 3, u = idx & 7;
        Al8[row*8 + (u ^ (row & 7))] = Ag[(size_t)(m0 + row)*48 + k0u + u];
        Bl8[row*8 + (u ^ (row & 7))] = Bg[(size_t)(n0 + row)*48 + k0u + u];
      }
      __syncthreads();
      #pragma unroll
      for (int kk = 0; kk < 2; ++kk){
        int arow = wave*16 + l15;
        s16x8 af = Al8[arow*8 + ((kk*4 + sub) ^ (arow & 7))];
        #pragma unroll
        for (int c = 0; c < 4; ++c){
          int brow = c*16 + l15;
          s16x8 bf = Bl8[brow*8 + ((kk*4 + sub) ^ (brow & 7))];
          acc[c] = __builtin_amdgcn_mfma_f32_16x16x32_bf16(af, bf, acc[c], 0, 0, 0);
        }
      }
      __syncthreads();
    }
    int which = blockIdx.x / 6;
    int cb = n0 - which*384;
    #pragma unroll
    for (int c = 0; c < 4; ++c){
      int col = cb + c*16 + l15;
      #pragma unroll
      for (int r = 0; r < 4; ++r){
        int row = m0 + wave*16 + sub*4 + r;
        float v = acc[c][r];
        if (which == 3){
          float t = v + bg[col];
          g[(size_t)row*384 + col] = 1.f/(1.f + __expf(-t));
        } else {
          int h = col/24, d = col - h*24;
          float* dst = which == 0 ? qT : which == 1 ? kT : vT;
          dst[((size_t)(h << 10) + row)*24 + d] = v;
        }
      }
    }
  }
}

// ---------------- z bias: LN(z) @ w_z via bf16 MFMA; stats via MFMA row-sums ----------------
__global__ __launch_bounds__(256) void zbias_kernel(const float* __restrict__ z, const unsigned short* __restrict__ wwB,
                                                    const float* __restrict__ TU, unsigned short* __restrict__ pb, long roff){
  __shared__ short zt[64*16*8];
  __shared__ short zq[64*16*8];
  __shared__ float2 stats[64];
  __shared__ float accT[64][17];
  int tid = threadIdx.x;
  int wave = tid >> 6, lane = tid & 63;
  int h = lane & 15, sub = lane >> 4;
  s16x8 bfr[4];
  #pragma unroll
  for (int kc = 0; kc < 4; ++kc)
    #pragma unroll
    for (int j = 0; j < 8; ++j) bfr[kc][j] = (short)wwB[(kc*32 + sub*8 + j)*16 + h];
  s16x8 ones1;
  #pragma unroll
  for (int j = 0; j < 8; ++j) ones1[j] = (h == 0) ? (short)0x3F80 : (short)0;
  int eh = tid >> 4, epl0 = (tid & 15)*4;
  float Te = TU[eh], Ue = TU[16 + eh];
  for (int rep = 0; rep < REP_ZB; ++rep){
    const float* zr = z + (size_t)rep*roff;
    for (int it = 0; it < 4; ++it){
      int tile = blockIdx.x + it*4096;
      size_t pairBase = (size_t)tile*64;
      const f32x4* zin = ((const f32x4*)zr) + pairBase*32;
      #pragma unroll
      for (int i = 0; i < 8; ++i){
        int f4i = i*256 + tid;
        f32x4 v = zin[f4i];
        int pair = f4i >> 5, c4 = f4i & 31;
        unsigned lo  = pk_bf(v.x, v.y),         hi  = pk_bf(v.z, v.w);
        unsigned qlo = pk_bf(v.x*v.x, v.y*v.y), qhi = pk_bf(v.z*v.z, v.w*v.w);
        int idx = (pair*16 + ((c4 >> 1) ^ (pair & 7)))*2 + (c4 & 1);
        ((uint2*)zt)[idx] = make_uint2(lo, hi);
        ((uint2*)zq)[idx] = make_uint2(qlo, qhi);
      }
      __syncthreads();
      int row = wave*16 + h;
      f32x4 acc  = {0.f, 0.f, 0.f, 0.f};
      f32x4 accS = {0.f, 0.f, 0.f, 0.f};
      f32x4 accQ = {0.f, 0.f, 0.f, 0.f};
      const s16x8* zt8 = (const s16x8*)zt;
      const s16x8* zq8 = (const s16x8*)zq;
      #pragma unroll
      for (int kc = 0; kc < 4; ++kc){
        int u = (kc*4 + sub) ^ (row & 7);
        s16x8 af = zt8[row*16 + u];
        s16x8 aq = zq8[row*16 + u];
        acc  = __builtin_amdgcn_mfma_f32_16x16x32_bf16(af, bfr[kc], acc, 0, 0, 0);
        accS = __builtin_amdgcn_mfma_f32_16x16x32_bf16(af, ones1, accS, 0, 0, 0);
        accQ = __builtin_amdgcn_mfma_f32_16x16x32_bf16(aq, ones1, accQ, 0, 0, 0);
      }
      #pragma unroll
      for (int r = 0; r < 4; ++r) accT[wave*16 + sub*4 + r][h] = acc[r];
      if (h == 0){
        #pragma unroll
        for (int r = 0; r < 4; ++r){
          float mu = accS[r]*(1.f/128.f);
          float var = accQ[r]*(1.f/128.f) - mu*mu;
          stats[wave*16 + sub*4 + r] = make_float2(mu, rsqrtf(var + 1e-5f));
        }
      }
      __syncthreads();
      ushort4 ov;
      {
        float2 st0 = stats[epl0+0], st1 = stats[epl0+1], st2 = stats[epl0+2], st3 = stats[epl0+3];
        ov.x = f2bf(st0.y*(accT[epl0+0][eh] - st0.x*Te) + Ue);
        ov.y = f2bf(st1.y*(accT[epl0+1][eh] - st1.x*Te) + Ue);
        ov.z = f2bf(st2.y*(accT[epl0+2][eh] - st2.x*Te) + Ue);
        ov.w = f2bf(st3.y*(accT[epl0+3][eh] - st3.x*Te) + Ue);
      }
      *(ushort4*)(pb + ((size_t)eh << 20) + pairBase + epl0) = ov;
      __syncthreads();
    }
  }
}

// ---------------- fused attention ----------------
__global__ __launch_bounds__(1024) void attn_kernel(const float* __restrict__ qT, const float* __restrict__ kT,
                                                    const float* __restrict__ vT, const unsigned short* __restrict__ pb,
                                                    const float* __restrict__ mask, const float* __restrict__ g,
                                                    unsigned short* __restrict__ ogB, long roff){
  __shared__ float mlds[16][64][29];
  int qb = blockIdx.x, h = blockIdx.y;
  int wave = threadIdx.x >> 6, lane = threadIdx.x & 63;
  int q = qb*64 + lane;
  for (int rep = 0; rep < REP_ATTN; ++rep){
    const float* qTr = qT + (size_t)rep*roff;
    const float* kTr = kT + (size_t)rep*roff;
    const float* vTr = vT + (size_t)rep*roff;
    const unsigned short* pbr = pb + (size_t)rep*roff;
    const float4* qp = (const float4*)(qTr + ((size_t)(h << 10) + q)*24);
    float qv[24];
    #pragma unroll
    for (int i = 0; i < 6; ++i){ float4 t = qp[i]; qv[4*i] = t.x; qv[4*i+1] = t.y; qv[4*i+2] = t.z; qv[4*i+3] = t.w; }
    const unsigned short* pbrow = pbr + ((size_t)h << 20) + (size_t)q*1024;
    float m = -1e30f, lsum = 0.f, ov[24];
    #pragma unroll
    for (int i = 0; i < 24; ++i) ov[i] = 0.f;
    int kk0 = wave*64;
    for (int grp = 0; grp < 16; ++grp){
      int kkb = kk0 + grp*4;
      s16x4 pbv = *(const s16x4*)(pbrow + kkb);
      float4 mk = *(const float4*)(mask + kkb);
      float lg[4];
      #pragma unroll
      for (int j = 0; j < 4; ++j){
        const float4* kp = (const float4*)(kTr + ((size_t)(h << 10) + kkb + j)*24);
        float d0 = 0.f, d1 = 0.f, d2 = 0.f, d3 = 0.f;
        #pragma unroll
        for (int i = 0; i < 6; ++i){
          float4 kf = kp[i];
          d0 += qv[4*i]*kf.x; d1 += qv[4*i+1]*kf.y; d2 += qv[4*i+2]*kf.z; d3 += qv[4*i+3]*kf.w;
        }
        float mb = j == 0 ? mk.x : j == 1 ? mk.y : j == 2 ? mk.z : mk.w;
        lg[j] = (d0 + d1) + (d2 + d3) + bf2f((unsigned short)pbv[j]) + 1e9f*(mb - 1.f);
      }
      float gm = fmaxf(fmaxf(lg[0], lg[1]), fmaxf(lg[2], lg[3]));
      if (gm > m){
        float corr = __expf(m - gm);
        lsum *= corr;
        #pragma unroll
        for (int i = 0; i < 24; ++i) ov[i] *= corr;
        m = gm;
      }
      #pragma unroll
      for (int j = 0; j < 4; ++j){
        float p = __expf(lg[j] - m);
        lsum += p;
        const float4* vp = (const float4*)(vTr + ((size_t)(h << 10) + kkb + j)*24);
        #pragma unroll
        for (int i = 0; i < 6; ++i){
          float4 vf = vp[i];
          ov[4*i]   += p*vf.x;
          ov[4*i+1] += p*vf.y;
          ov[4*i+2] += p*vf.z;
          ov[4*i+3] += p*vf.w;
        }
      }
    }
    mlds[wave][lane][0] = m; mlds[wave][lane][1] = lsum;
    #pragma unroll
    for (int i = 0; i < 24; ++i) mlds[wave][lane][2+i] = ov[i];
    __syncthreads();
    #pragma unroll
    for (int s2 = 8; s2 >= 1; s2 >>= 1){
      if (wave < s2){
        float m1 = mlds[wave][lane][0],    l1 = mlds[wave][lane][1];
        float m2 = mlds[wave+s2][lane][0], l2 = mlds[wave+s2][lane][1];
        float nm = fmaxf(m1, m2);
        float c1 = __expf(m1 - nm), c2 = __expf(m2 - nm);
        mlds[wave][lane][0] = nm;
        mlds[wave][lane][1] = l1*c1 + l2*c2;
        #pragma unroll
        for (int i = 0; i < 24; ++i)
          mlds[wave][lane][2+i] = mlds[wave][lane][2+i]*c1 + mlds[wave+s2][lane][2+i]*c2;
      }
      __syncthreads();
    }
    if (wave == 0){
      float inv = 1.f/mlds[0][lane][1];
      size_t base = (size_t)q*384 + h*24;
      unsigned ow[12];
      #pragma unroll
      for (int i2 = 0; i2 < 6; ++i2){
        float4 gv = *(const float4*)(g + base + i2*4);
        float o0 = mlds[0][lane][2 + 4*i2],     o1 = mlds[0][lane][3 + 4*i2];
        float o2 = mlds[0][lane][4 + 4*i2],     o3 = mlds[0][lane][5 + 4*i2];
        ow[2*i2]   = pk_bf(gv.x*o0*inv, gv.y*o1*inv);
        ow[2*i2+1] = pk_bf(gv.z*o2*inv, gv.w*o3*inv);
      }
      uint4* dst = (uint4*)(ogB + base);
      dst[0] = make_uint4(ow[0], ow[1], ow[2],  ow[3]);
      dst[1] = make_uint4(ow[4], ow[5], ow[6],  ow[7]);
      dst[2] = make_uint4(ow[8], ow[9], ow[10], ow[11]);
    }
    __syncthreads();
  }
}

// ---------------- final projection via MFMA ----------------
__global__ __launch_bounds__(256) void gemm_out(const unsigned short* __restrict__ AB,
                                                const unsigned short* __restrict__ wBo,
                                                const float* __restrict__ bo, float* __restrict__ dst, long roff){
  __shared__ short Al[64*8*8];
  __shared__ short Bl[64*8*8];
  int tid = threadIdx.x;
  int wave = tid >> 6, lane = tid & 63, l15 = lane & 15, sub = lane >> 4;
  int n0 = blockIdx.x*64, m0 = blockIdx.y*64;
  s16x8* Al8 = (s16x8*)Al; s16x8* Bl8 = (s16x8*)Bl;
  for (int rep = 0; rep < REP_OUT; ++rep){
    const s16x8* Ag = (const s16x8*)(AB + (size_t)rep*roff);
    const s16x8* Bg = (const s16x8*)(wBo + (size_t)rep*roff);
    f32x4 acc[4];
    #pragma unroll
    for (int c = 0; c < 4; ++c) acc[c] = (f32x4){0.f,0.f,0.f,0.f};
    for (int ks = 0; ks < 6; ++ks){
      int k0u = ks*8;
      #pragma unroll
      for (int j = 0; j < 2; ++j){
        int idx = tid*2 + j;
        int row = idx >> 3, u = idx & 7;
        Al8[row*8 + (u ^ (row & 7))] = Ag[(size_t)(m0 + row)*48 + k0u + u];
        Bl8[row*8 + (u ^ (row & 7))] = Bg[(size_t)(n0 + row)*48 + k0u + u];
      }
      __syncthreads();
      #pragma unroll
      for (int kk = 0; kk < 2; ++kk){
        int arow = wave*16 + l15;
        s16x8 af = Al8[arow*8 + ((kk*4 + sub) ^ (arow & 7))];
        #pragma unroll
        for (int c = 0; c < 4; ++c){
          int brow = c*16 + l15;
          s16x8 bf = Bl8[brow*8 + ((kk*4 + sub) ^ (brow & 7))];
          acc[c] = __builtin_amdgcn_mfma_f32_16x16x32_bf16(af, bf, acc[c], 0, 0, 0);
        }
      }
      __syncthreads();
    }
    #pragma unroll
    for (int c = 0; c < 4; ++c){
      int col = n0 + c*16 + l15;
      float b = bo[col];
      #pragma unroll
      for (int r = 0; r < 4; ++r){
        int row = m0 + wave*16 + sub*4 + r;
        dst[(size_t)row*384 + col] = acc[c][r] + b;
      }
    }
  }
}

extern "C" void kernel_launch(void* const* d_in, const int* in_sizes, int n_in,
                              void* d_out, int out_size, void* d_ws, size_t ws_size,
                              hipStream_t stream){
  const float* a      = (const float*)d_in[0];
  const float* z      = (const float*)d_in[1];
  const float* mask   = (const float*)d_in[2];
  const float* ln_a_w = (const float*)d_in[3];
  const float* ln_a_b = (const float*)d_in[4];
  const float* ln_z_w = (const float*)d_in[5];
  const float* ln_z_b = (const float*)d_in[6];
  const float* w_z    = (const float*)d_in[7];
  const float* wq     = (const float*)d_in[8];
  const float* wk     = (const float*)d_in[9];
  const float* wv     = (const float*)d_in[10];
  const float* wg     = (const float*)d_in[11];
  const float* bg     = (const float*)d_in[12];
  const float* wo     = (const float*)d_in[13];
  const float* bo     = (const float*)d_in[14];

  char* ws = (char*)d_ws;
  unsigned short* a_lnB = (unsigned short*)(ws + ((size_t)0u));
  unsigned short* wBall = (unsigned short*)(ws + ((size_t)1u << 20));
  float* qT   = (float*)(ws + ((size_t)4u << 20));
  float* kT   = (float*)(ws + ((size_t)6u << 20));
  float* vT   = (float*)(ws + ((size_t)8u << 20));
  float* g    = (float*)(ws + ((size_t)10u << 20));
  unsigned short* ogB = (unsigned short*)(ws + ((size_t)12u << 20));
  unsigned short* wwB = (unsigned short*)(ws + ((size_t)14u << 20));
  float* TU   = (float*)(ws + ((size_t)14u << 20) + 8192);
  unsigned short* pb  = (unsigned short*)(ws + ((size_t)24u << 20));

  long roff = 0;
  hipLaunchKernelGGL(prep_kernel, dim3(437), dim3(256), 0, stream, a, ln_a_w, ln_a_b,
                     ln_z_w, ln_z_b, w_z, wq, wk, wv, wg, wo, a_lnB, wBall, wwB, TU, roff);
  hipLaunchKernelGGL(qkvg_kernel, dim3(24,16), dim3(256), 0, stream, a_lnB, wBall, bg, qT, kT, vT, g, roff);
  hipLaunchKernelGGL(zbias_kernel, dim3(4096), dim3(256), 0, stream, z, wwB, TU, pb, roff);
  hipLaunchKernelGGL(attn_kernel, dim3(16,16), dim3(1024), 0, stream, qT, kT, vT, pb, mask, g, ogB, roff);
  hipLaunchKernelGGL(gemm_out, dim3(6,16), dim3(256), 0, stream, ogB, wBall + (size_t)4*384*384, bo, (float*)d_out, roff);
}

// Round 7
// 220.564 us; speedup vs baseline: 20.8740x; 20.8740x over previous
//
#include <hip/hip_runtime.h>
#include <hip/hip_bf16.h>

typedef float f32x4 __attribute__((ext_vector_type(4)));
typedef short s16x8 __attribute__((ext_vector_type(8)));
typedef short s16x4 __attribute__((ext_vector_type(4)));

__device__ __forceinline__ unsigned short f2bf(float x){
  unsigned u = __float_as_uint(x);
  u += 0x7fffu + ((u >> 16) & 1u);
  return (unsigned short)(u >> 16);
}
__device__ __forceinline__ float bf2f(unsigned short h){
  return __uint_as_float(((unsigned)h) << 16);
}
__device__ __forceinline__ unsigned pk_bf(float a, float b){
  __hip_bfloat162 t = __float22bfloat162_rn(make_float2(a, b));
  return *reinterpret_cast<unsigned*>(&t);
}

// ---------------- prep: weight transpose->bf16 (0..179), ln_a (180..435), setup (436) ----------------
__global__ __launch_bounds__(256) void prep_kernel(const float* __restrict__ a, const float* __restrict__ ln_a_w,
                             const float* __restrict__ ln_a_b, const float* __restrict__ lnzw,
                             const float* __restrict__ lnzb, const float* __restrict__ w_z,
                             const float* __restrict__ wq, const float* __restrict__ wk,
                             const float* __restrict__ wv, const float* __restrict__ wg,
                             const float* __restrict__ wo,
                             unsigned short* __restrict__ a_lnB, unsigned short* __restrict__ wBall,
                             unsigned short* __restrict__ wwB, float* __restrict__ TU){
  int bid = blockIdx.x, tid = threadIdx.x;
  if (bid < 180){
    __shared__ float t[64][65];
    int mat = bid/36, tt = bid - mat*36;
    int c0 = (tt % 6)*64, k0 = (tt / 6)*64;
    const float* src = mat == 0 ? wq : mat == 1 ? wk : mat == 2 ? wv : mat == 3 ? wg : wo;
    int r = tid >> 4, c4 = (tid & 15)*4;
    #pragma unroll
    for (int rr = 0; rr < 4; ++rr){
      float4 v = *(const float4*)(src + (size_t)(k0 + r + rr*16)*384 + c0 + c4);
      t[r + rr*16][c4+0] = v.x; t[r + rr*16][c4+1] = v.y;
      t[r + rr*16][c4+2] = v.z; t[r + rr*16][c4+3] = v.w;
    }
    __syncthreads();
    float scale = (mat == 0) ? 0.20412414523193154f : 1.f;
    int cc = tid >> 2, kp = (tid & 3)*16;
    unsigned ow[8];
    #pragma unroll
    for (int j = 0; j < 8; ++j)
      ow[j] = pk_bf(t[kp + 2*j][cc]*scale, t[kp + 2*j + 1][cc]*scale);
    unsigned short* dst = wBall + ((size_t)(mat*384 + c0 + cc)*384 + k0 + kp);
    *(uint4*)dst       = make_uint4(ow[0], ow[1], ow[2], ow[3]);
    *(uint4*)(dst + 8) = make_uint4(ow[4], ow[5], ow[6], ow[7]);
  } else if (bid < 436){
    int r = (bid - 180)*4 + (tid >> 6), l = tid & 63;
    const float* ap = a + (size_t)r*384;
    float x[6]; float s = 0.f, sq = 0.f;
    #pragma unroll
    for (int i = 0; i < 6; ++i){ x[i] = ap[i*64 + l]; s += x[i]; sq += x[i]*x[i]; }
    #pragma unroll
    for (int off = 32; off; off >>= 1){ s += __shfl_xor(s, off); sq += __shfl_xor(sq, off); }
    float mu = s*(1.f/384.f);
    float var = sq*(1.f/384.f) - mu*mu;
    float rs = rsqrtf(var + 1e-5f);
    #pragma unroll
    for (int i = 0; i < 6; ++i){ int c = i*64 + l; a_lnB[(size_t)r*384 + c] = f2bf((x[i]-mu)*rs*ln_a_w[c] + ln_a_b[c]); }
  } else {
    if (tid < 128){
      float lw = lnzw[tid];
      #pragma unroll
      for (int h = 0; h < 16; ++h) wwB[tid*16 + h] = f2bf(lw * w_z[tid*16 + h]);
    }
    if (tid < 16){
      float T = 0.f, U = 0.f;
      for (int c = 0; c < 128; ++c){ T += lnzw[c]*w_z[c*16 + tid]; U += lnzb[c]*w_z[c*16 + tid]; }
      TU[tid] = T; TU[16 + tid] = U;
    }
  }
}

// ---------------- fused QKVG: [1024x384]bf16 @ [384x1536]bf16 via MFMA ----------------
__global__ __launch_bounds__(256) void qkvg_kernel(const unsigned short* __restrict__ AB,
                                                   const unsigned short* __restrict__ wBt,
                                                   const float* __restrict__ bg,
                                                   float* __restrict__ qT, float* __restrict__ kT,
                                                   float* __restrict__ vT, float* __restrict__ g){
  __shared__ short Al[64*8*8];
  __shared__ short Bl[64*8*8];
  int tid = threadIdx.x;
  int wave = tid >> 6, lane = tid & 63, l15 = lane & 15, sub = lane >> 4;
  int n0 = blockIdx.x*64, m0 = blockIdx.y*64;
  f32x4 acc[4];
  #pragma unroll
  for (int c = 0; c < 4; ++c) acc[c] = (f32x4){0.f,0.f,0.f,0.f};
  const s16x8* Ag = (const s16x8*)AB;
  const s16x8* Bg = (const s16x8*)wBt;
  s16x8* Al8 = (s16x8*)Al; s16x8* Bl8 = (s16x8*)Bl;
  for (int ks = 0; ks < 6; ++ks){
    int k0u = ks*8;
    #pragma unroll
    for (int j = 0; j < 2; ++j){
      int idx = tid*2 + j;
      int row = idx >> 3, u = idx & 7;
      Al8[row*8 + (u ^ (row & 7))] = Ag[(size_t)(m0 + row)*48 + k0u + u];
      Bl8[row*8 + (u ^ (row & 7))] = Bg[(size_t)(n0 + row)*48 + k0u + u];
    }
    __syncthreads();
    #pragma unroll
    for (int kk = 0; kk < 2; ++kk){
      int arow = wave*16 + l15;
      s16x8 af = Al8[arow*8 + ((kk*4 + sub) ^ (arow & 7))];
      #pragma unroll
      for (int c = 0; c < 4; ++c){
        int brow = c*16 + l15;
        s16x8 bf = Bl8[brow*8 + ((kk*4 + sub) ^ (brow & 7))];
        acc[c] = __builtin_amdgcn_mfma_f32_16x16x32_bf16(af, bf, acc[c], 0, 0, 0);
      }
    }
    __syncthreads();
  }
  int which = blockIdx.x / 6;
  int cb = n0 - which*384;
  #pragma unroll
  for (int c = 0; c < 4; ++c){
    int col = cb + c*16 + l15;
    #pragma unroll
    for (int r = 0; r < 4; ++r){
      int row = m0 + wave*16 + sub*4 + r;
      float v = acc[c][r];
      if (which == 3){
        float t = v + bg[col];
        g[(size_t)row*384 + col] = 1.f/(1.f + __expf(-t));
      } else {
        int h = col/24, d = col - h*24;
        float* dst = which == 0 ? qT : which == 1 ? kT : vT;
        dst[((size_t)(h << 10) + row)*24 + d] = v;
      }
    }
  }
}

// ---------------- z bias v2: LN(z)@w_z via MFMA; Σz via ones-MFMA, Σz² via Gram-MFMA diag ----------------
__global__ __launch_bounds__(256) void zbias_kernel(const float* __restrict__ z, const unsigned short* __restrict__ wwB,
                                                    const float* __restrict__ TU, unsigned short* __restrict__ pb){
  __shared__ short zt[64*16*8];        // 64 pairs x 128 ch bf16, 16B-unit XOR swizzle (16 KB)
  __shared__ float sums[64];
  __shared__ float sqs[64];
  __shared__ float accT[64][17];       // transposed MFMA result for coalesced pb stores
  int tid = threadIdx.x;
  int wave = tid >> 6, lane = tid & 63;
  int h = lane & 15, sub = lane >> 4;
  s16x8 bfr[4];
  #pragma unroll
  for (int kc = 0; kc < 4; ++kc)
    #pragma unroll
    for (int j = 0; j < 8; ++j) bfr[kc][j] = (short)wwB[(kc*32 + sub*8 + j)*16 + h];
  s16x8 ones1;                         // B with col0 = 1.0 -> D[:,0] = row sums
  #pragma unroll
  for (int j = 0; j < 8; ++j) ones1[j] = (h == 0) ? (short)0x3F80 : (short)0;
  int eh = tid >> 4, epl0 = (tid & 15)*4;
  float Te = TU[eh], Ue = TU[16 + eh];
  for (int it = 0; it < 4; ++it){
    int tile = blockIdx.x + it*4096;
    size_t pairBase = (size_t)tile*64;
    const f32x4* zin = ((const f32x4*)z) + pairBase*32;
    #pragma unroll
    for (int i = 0; i < 8; ++i){
      int f4i = i*256 + tid;
      f32x4 v = zin[f4i];
      int pair = f4i >> 5, c4 = f4i & 31;
      unsigned lo  = pk_bf(v.x, v.y), hi = pk_bf(v.z, v.w);
      int idx = (pair*16 + ((c4 >> 1) ^ (pair & 7)))*2 + (c4 & 1);
      ((uint2*)zt)[idx] = make_uint2(lo, hi);
    }
    __syncthreads();
    int row = wave*16 + h;
    f32x4 acc  = {0.f, 0.f, 0.f, 0.f};
    f32x4 accS = {0.f, 0.f, 0.f, 0.f};
    f32x4 accG = {0.f, 0.f, 0.f, 0.f};
    const s16x8* zt8 = (const s16x8*)zt;
    #pragma unroll
    for (int kc = 0; kc < 4; ++kc){
      int u = (kc*4 + sub) ^ (row & 7);
      s16x8 af = zt8[row*16 + u];
      acc  = __builtin_amdgcn_mfma_f32_16x16x32_bf16(af, bfr[kc], acc, 0, 0, 0);
      accS = __builtin_amdgcn_mfma_f32_16x16x32_bf16(af, ones1, accS, 0, 0, 0);
      accG = __builtin_amdgcn_mfma_f32_16x16x32_bf16(af, af, accG, 0, 0, 0);
    }
    #pragma unroll
    for (int r = 0; r < 4; ++r) accT[wave*16 + sub*4 + r][h] = acc[r];
    if (h == 0){
      #pragma unroll
      for (int r = 0; r < 4; ++r) sums[wave*16 + sub*4 + r] = accS[r];
    }
    if (sub == (h >> 2)){
      int r = h & 3;
      float vq = r == 0 ? accG[0] : r == 1 ? accG[1] : r == 2 ? accG[2] : accG[3];
      sqs[wave*16 + h] = vq;
    }
    __syncthreads();
    float mus[4], rss[4];
    #pragma unroll
    for (int rr = 0; rr < 4; ++rr){
      float mu = sums[epl0+rr]*(1.f/128.f);
      float var = sqs[epl0+rr]*(1.f/128.f) - mu*mu;
      mus[rr] = mu; rss[rr] = rsqrtf(var + 1e-5f);
    }
    ushort4 ov;
    ov.x = f2bf(rss[0]*(accT[epl0+0][eh] - mus[0]*Te) + Ue);
    ov.y = f2bf(rss[1]*(accT[epl0+1][eh] - mus[1]*Te) + Ue);
    ov.z = f2bf(rss[2]*(accT[epl0+2][eh] - mus[2]*Te) + Ue);
    ov.w = f2bf(rss[3]*(accT[epl0+3][eh] - mus[3]*Te) + Ue);
    *(ushort4*)(pb + ((size_t)eh << 20) + pairBase + epl0) = ov;
    __syncthreads();
  }
}

// ---------------- attn v3: per-wave LDS staging (K/V f32 + pb bf16), prefetch, no main-loop barriers ----------------
// grid (16 qb, 16 h), 512 threads = 8 waves; wave w owns kk in [w*128, w*128+128), 4 chunks of 32.
__global__ __launch_bounds__(512) void attn_kernel(const float* __restrict__ qT, const float* __restrict__ kT,
                                                   const float* __restrict__ vT, const unsigned short* __restrict__ pb,
                                                   const float* __restrict__ mask, const float* __restrict__ g,
                                                   unsigned short* __restrict__ ogB){
  __shared__ float lds[8*2816];    // per wave: K 768f | V 768f | pbL 64*40 ushort (1280f) = 2816 floats (11264 B); total 90112 B
  int wave = threadIdx.x >> 6, lane = threadIdx.x & 63;
  int qb = blockIdx.x, h = blockIdx.y;
  int q = qb*64 + lane;
  float* wl = lds + wave*2816;
  float* Kf = wl;
  float* Vf = wl + 768;
  unsigned short* pbL = (unsigned short*)(wl + 1536);
  const float4* qp = (const float4*)(qT + ((size_t)(h << 10) + q)*24);
  float qv[24];
  #pragma unroll
  for (int i = 0; i < 6; ++i){ float4 t = qp[i]; qv[4*i] = t.x; qv[4*i+1] = t.y; qv[4*i+2] = t.z; qv[4*i+3] = t.w; }
  float m = -1e30f, lsum = 0.f, ov[24];
  #pragma unroll
  for (int i = 0; i < 24; ++i) ov[i] = 0.f;
  int kkw = wave*128;
  int r4 = lane >> 2, p4 = lane & 3;
  const unsigned short* pbBase = pb + ((size_t)h << 20) + (size_t)(qb*64)*1024;
  float4 kr[3], vr[3]; uint4 pr[4];
  auto ISSUE = [&](int c){
    int kkc = kkw + c*32;
    const float4* kg = (const float4*)(kT + ((size_t)(h << 10) + kkc)*24);
    const float4* vg = (const float4*)(vT + ((size_t)(h << 10) + kkc)*24);
    #pragma unroll
    for (int i = 0; i < 3; ++i){ kr[i] = kg[lane*3 + i]; vr[i] = vg[lane*3 + i]; }
    #pragma unroll
    for (int i = 0; i < 4; ++i)
      pr[i] = *(const uint4*)(pbBase + (size_t)(r4 + 16*i)*1024 + kkc + p4*8);
  };
  auto STAGE = [&](){
    #pragma unroll
    for (int i = 0; i < 3; ++i){
      *(float4*)(Kf + lane*12 + i*4) = kr[i];
      *(float4*)(Vf + lane*12 + i*4) = vr[i];
    }
    #pragma unroll
    for (int i = 0; i < 4; ++i){
      int r = r4 + 16*i;
      *(uint4*)(pbL + r*40 + ((p4 ^ (r & 3)) << 3)) = pr[i];
    }
  };
  auto COMPUTE = [&](int c){
    int kkc = kkw + c*32;
    #pragma unroll
    for (int grp = 0; grp < 8; ++grp){
      s16x4 pbv = *(const s16x4*)(pbL + lane*40 + (((grp >> 1) ^ (lane & 3)) << 3) + ((grp & 1) << 2));
      float4 mk = *(const float4*)(mask + kkc + grp*4);
      float lg[4];
      #pragma unroll
      for (int j = 0; j < 4; ++j){
        const float4* kp = (const float4*)(Kf + (grp*4 + j)*24);
        float d0 = 0.f, d1 = 0.f, d2 = 0.f, d3 = 0.f;
        #pragma unroll
        for (int i = 0; i < 6; ++i){
          float4 kf = kp[i];
          d0 += qv[4*i]*kf.x; d1 += qv[4*i+1]*kf.y; d2 += qv[4*i+2]*kf.z; d3 += qv[4*i+3]*kf.w;
        }
        float mb = j == 0 ? mk.x : j == 1 ? mk.y : j == 2 ? mk.z : mk.w;
        lg[j] = (d0 + d1) + (d2 + d3) + bf2f((unsigned short)pbv[j]) + 1e9f*(mb - 1.f);
      }
      float gm = fmaxf(fmaxf(lg[0], lg[1]), fmaxf(lg[2], lg[3]));
      if (gm > m){
        float corr = __expf(m - gm);
        lsum *= corr;
        #pragma unroll
        for (int i = 0; i < 24; ++i) ov[i] *= corr;
        m = gm;
      }
      #pragma unroll
      for (int j = 0; j < 4; ++j){
        float p = __expf(lg[j] - m);
        lsum += p;
        const float4* vp = (const float4*)(Vf + (grp*4 + j)*24);
        #pragma unroll
        for (int i = 0; i < 6; ++i){
          float4 vf = vp[i];
          ov[4*i]   += p*vf.x;
          ov[4*i+1] += p*vf.y;
          ov[4*i+2] += p*vf.z;
          ov[4*i+3] += p*vf.w;
        }
      }
    }
  };
  ISSUE(0);
  #pragma unroll
  for (int c = 0; c < 4; ++c){
    STAGE();
    if (c < 3) ISSUE(c + 1);
    COMPUTE(c);
  }
  // ---- combine across 8 waves (reuse staging LDS; barrier first) ----
  __syncthreads();
  {
    float* cw = lds + ((size_t)wave*64 + lane)*27;
    cw[0] = m; cw[1] = lsum;
    #pragma unroll
    for (int i = 0; i < 24; ++i) cw[2+i] = ov[i];
  }
  __syncthreads();
  #pragma unroll
  for (int s2 = 4; s2 >= 1; s2 >>= 1){
    if (wave < s2){
      float* c1 = lds + ((size_t)wave*64 + lane)*27;
      float* c2 = lds + ((size_t)(wave + s2)*64 + lane)*27;
      float m1 = c1[0], l1 = c1[1], m2 = c2[0], l2 = c2[1];
      float nm = fmaxf(m1, m2);
      float f1 = __expf(m1 - nm), f2 = __expf(m2 - nm);
      c1[0] = nm; c1[1] = l1*f1 + l2*f2;
      #pragma unroll
      for (int i = 0; i < 24; ++i) c1[2+i] = c1[2+i]*f1 + c2[2+i]*f2;
    }
    __syncthreads();
  }
  if (wave == 0){
    float* c0 = lds + (size_t)lane*27;
    float inv = 1.f/c0[1];
    size_t base = (size_t)q*384 + h*24;
    unsigned ow[12];
    #pragma unroll
    for (int i2 = 0; i2 < 6; ++i2){
      float4 gv = *(const float4*)(g + base + i2*4);
      ow[2*i2]   = pk_bf(gv.x*c0[2 + 4*i2]*inv, gv.y*c0[3 + 4*i2]*inv);
      ow[2*i2+1] = pk_bf(gv.z*c0[4 + 4*i2]*inv, gv.w*c0[5 + 4*i2]*inv);
    }
    uint4* dst = (uint4*)(ogB + base);
    dst[0] = make_uint4(ow[0], ow[1], ow[2],  ow[3]);
    dst[1] = make_uint4(ow[4], ow[5], ow[6],  ow[7]);
    dst[2] = make_uint4(ow[8], ow[9], ow[10], ow[11]);
  }
}

// ---------------- final projection: ogB[1024x384]bf16 @ wo^T bf16 via MFMA, + bo ----------------
__global__ __launch_bounds__(256) void gemm_out(const unsigned short* __restrict__ AB,
                                                const unsigned short* __restrict__ wBo,
                                                const float* __restrict__ bo, float* __restrict__ dst){
  __shared__ short Al[64*8*8];
  __shared__ short Bl[64*8*8];
  int tid = threadIdx.x;
  int wave = tid >> 6, lane = tid & 63, l15 = lane & 15, sub = lane >> 4;
  int n0 = blockIdx.x*64, m0 = blockIdx.y*64;
  f32x4 acc[4];
  #pragma unroll
  for (int c = 0; c < 4; ++c) acc[c] = (f32x4){0.f,0.f,0.f,0.f};
  const s16x8* Ag = (const s16x8*)AB;
  const s16x8* Bg = (const s16x8*)wBo;
  s16x8* Al8 = (s16x8*)Al; s16x8* Bl8 = (s16x8*)Bl;
  for (int ks = 0; ks < 6; ++ks){
    int k0u = ks*8;
    #pragma unroll
    for (int j = 0; j < 2; ++j){
      int idx = tid*2 + j;
      int row = idx >> 3, u = idx & 7;
      Al8[row*8 + (u ^ (row & 7))] = Ag[(size_t)(m0 + row)*48 + k0u + u];
      Bl8[row*8 + (u ^ (row & 7))] = Bg[(size_t)(n0 + row)*48 + k0u + u];
    }
    __syncthreads();
    #pragma unroll
    for (int kk = 0; kk < 2; ++kk){
      int arow = wave*16 + l15;
      s16x8 af = Al8[arow*8 + ((kk*4 + sub) ^ (arow & 7))];
      #pragma unroll
      for (int c = 0; c < 4; ++c){
        int brow = c*16 + l15;
        s16x8 bf = Bl8[brow*8 + ((kk*4 + sub) ^ (brow & 7))];
        acc[c] = __builtin_amdgcn_mfma_f32_16x16x32_bf16(af, bf, acc[c], 0, 0, 0);
      }
    }
    __syncthreads();
  }
  #pragma unroll
  for (int c = 0; c < 4; ++c){
    int col = n0 + c*16 + l15;
    float b = bo[col];
    #pragma unroll
    for (int r = 0; r < 4; ++r){
      int row = m0 + wave*16 + sub*4 + r;
      dst[(size_t)row*384 + col] = acc[c][r] + b;
    }
  }
}

extern "C" void kernel_launch(void* const* d_in, const int* in_sizes, int n_in,
                              void* d_out, int out_size, void* d_ws, size_t ws_size,
                              hipStream_t stream){
  const float* a      = (const float*)d_in[0];
  const float* z      = (const float*)d_in[1];
  const float* mask   = (const float*)d_in[2];
  const float* ln_a_w = (const float*)d_in[3];
  const float* ln_a_b = (const float*)d_in[4];
  const float* ln_z_w = (const float*)d_in[5];
  const float* ln_z_b = (const float*)d_in[6];
  const float* w_z    = (const float*)d_in[7];
  const float* wq     = (const float*)d_in[8];
  const float* wk     = (const float*)d_in[9];
  const float* wv     = (const float*)d_in[10];
  const float* wg     = (const float*)d_in[11];
  const float* bg     = (const float*)d_in[12];
  const float* wo     = (const float*)d_in[13];
  const float* bo     = (const float*)d_in[14];

  char* ws = (char*)d_ws;
  unsigned short* a_lnB = (unsigned short*)(ws + ((size_t)0u));
  unsigned short* wBall = (unsigned short*)(ws + ((size_t)1u << 20));
  float* qT   = (float*)(ws + ((size_t)4u << 20));
  float* kT   = (float*)(ws + ((size_t)6u << 20));
  float* vT   = (float*)(ws + ((size_t)8u << 20));
  float* g    = (float*)(ws + ((size_t)10u << 20));
  unsigned short* ogB = (unsigned short*)(ws + ((size_t)12u << 20));
  unsigned short* wwB = (unsigned short*)(ws + ((size_t)14u << 20));
  float* TU   = (float*)(ws + ((size_t)14u << 20) + 8192);
  unsigned short* pb  = (unsigned short*)(ws + ((size_t)24u << 20));

  hipLaunchKernelGGL(prep_kernel, dim3(437), dim3(256), 0, stream, a, ln_a_w, ln_a_b,
                     ln_z_w, ln_z_b, w_z, wq, wk, wv, wg, wo, a_lnB, wBall, wwB, TU);
  hipLaunchKernelGGL(qkvg_kernel, dim3(24,16), dim3(256), 0, stream, a_lnB, wBall, bg, qT, kT, vT, g);
  hipLaunchKernelGGL(zbias_kernel, dim3(4096), dim3(256), 0, stream, z, wwB, TU, pb);
  hipLaunchKernelGGL(attn_kernel, dim3(16,16), dim3(512), 0, stream, qT, kT, vT, pb, mask, g, ogB);
  hipLaunchKernelGGL(gemm_out, dim3(6,16), dim3(256), 0, stream, ogB, wBall + (size_t)4*384*384, bo, (float*)d_out);
}